// Round 12
// baseline (1261.608 us; speedup 1.0000x reference)
//
#include <hip/hip_runtime.h>
#include <cstdint>
#include <cstddef>

#define DEV __device__ __forceinline__

// ============================ threefry2x32 (JAX) ============================
struct TFKey { uint32_t a, b; };

DEV uint32_t rotl32(uint32_t x, uint32_t r){ return (x << r) | (x >> (32u - r)); }

DEV TFKey tf2x32(TFKey k, uint32_t x0, uint32_t x1){
  uint32_t ks0 = k.a, ks1 = k.b, ks2 = k.a ^ k.b ^ 0x1BD11BDAu;
  x0 += ks0; x1 += ks1;
  x0 += x1; x1 = rotl32(x1,13); x1 ^= x0;
  x0 += x1; x1 = rotl32(x1,15); x1 ^= x0;
  x0 += x1; x1 = rotl32(x1,26); x1 ^= x0;
  x0 += x1; x1 = rotl32(x1, 6); x1 ^= x0;
  x0 += ks1; x1 += ks2 + 1u;
  x0 += x1; x1 = rotl32(x1,17); x1 ^= x0;
  x0 += x1; x1 = rotl32(x1,29); x1 ^= x0;
  x0 += x1; x1 = rotl32(x1,16); x1 ^= x0;
  x0 += x1; x1 = rotl32(x1,24); x1 ^= x0;
  x0 += ks2; x1 += ks0 + 2u;
  x0 += x1; x1 = rotl32(x1,13); x1 ^= x0;
  x0 += x1; x1 = rotl32(x1,15); x1 ^= x0;
  x0 += x1; x1 = rotl32(x1,26); x1 ^= x0;
  x0 += x1; x1 = rotl32(x1, 6); x1 ^= x0;
  x0 += ks0; x1 += ks1 + 3u;
  x0 += x1; x1 = rotl32(x1,17); x1 ^= x0;
  x0 += x1; x1 = rotl32(x1,29); x1 ^= x0;
  x0 += x1; x1 = rotl32(x1,16); x1 ^= x0;
  x0 += x1; x1 = rotl32(x1,24); x1 ^= x0;
  x0 += ks1; x1 += ks2 + 4u;
  x0 += x1; x1 = rotl32(x1,13); x1 ^= x0;
  x0 += x1; x1 = rotl32(x1,15); x1 ^= x0;
  x0 += x1; x1 = rotl32(x1,26); x1 ^= x0;
  x0 += x1; x1 = rotl32(x1, 6); x1 ^= x0;
  x0 += ks2; x1 += ks0 + 5u;
  return TFKey{x0, x1};
}

// jax_threefry_partitionable = True semantics (default since jax 0.4.36)
DEV TFKey tf_child(TFKey k, uint32_t i){ return tf2x32(k, 0u, i); }
DEV uint32_t rb32(TFKey k){ TFKey o = tf2x32(k, 0u, 0u); return o.a ^ o.b; }

// jax.random.uniform(key, (), f32, 0, 1)
DEV float u01(TFKey k){
  uint32_t bits = rb32(k);
  return __uint_as_float((bits >> 9) | 0x3F800000u) - 1.0f;
}

// correctly-rounded f32 transcendentals via f64 (match glibc CR libm)
DEV float cr_logf(float x){ return (float)log((double)x); }
DEV float cr_expf(float x){ return (float)exp((double)x); }
DEV float cr_powf(float x, float y){ return (float)pow((double)x, (double)y); }

// XLA ErfInv32 (Giles) — exact op order, no FP contraction
DEV float xla_erfinv(float x){
  #pragma clang fp contract(off)
  float w = -(float)log1p((double)(-(x*x)));
  float p;
  if (w < 5.0f){
    w = w - 2.5f;
    p = 2.81022636e-08f;
    p = 3.43273939e-07f + p*w;
    p = -3.5233877e-06f + p*w;
    p = -4.39150654e-06f + p*w;
    p = 0.00021858087f  + p*w;
    p = -0.00125372503f + p*w;
    p = -0.00417768164f + p*w;
    p = 0.246640727f    + p*w;
    p = 1.50140941f     + p*w;
  } else {
    w = sqrtf(w) - 3.0f;
    p = -0.000200214257f;
    p = 0.000100950558f + p*w;
    p = 0.00134934322f  + p*w;
    p = -0.00367342844f + p*w;
    p = 0.00573950773f  + p*w;
    p = -0.0076224613f  + p*w;
    p = 0.00943887047f  + p*w;
    p = 1.00167406f     + p*w;
    p = 2.83297682f     + p*w;
  }
  return p*x;
}

// jax.random.normal: u = uniform(lo=nextafter(-1,0), hi=1); sqrt(2)*erfinv(u)
DEV float normal_f(TFKey k){
  #pragma clang fp contract(off)
  uint32_t bits = rb32(k);
  float f = __uint_as_float((bits >> 9) | 0x3F800000u) - 1.0f;
  const float lo = -0x1.fffffep-1f;      // nextafter(-1, 0)
  float u = f*2.0f + lo;                  // (hi - lo) rounds to exactly 2.0f
  u = fmaxf(lo, u);
  return 0x1.6a09e6p+0f * xla_erfinv(u);  // np.float32(sqrt(2))
}

// jax _gamma_one (Marsaglia–Tsang), log_space=False
DEV float gamma_one(TFKey ek, float alpha){
  #pragma clang fp contract(off)
  TFKey key = tf_child(ek, 0u);
  TFKey sub = tf_child(ek, 1u);
  bool bm = (alpha >= 1.0f);
  float a_orig = alpha;
  float ab = bm ? alpha : (alpha + 1.0f);
  const float c13 = 0x1.555556p-2f;       // float32(1/3)
  float d = ab - c13;
  float c = c13 / sqrtf(d);
  float X = 0.0f, Vv = 1.0f, U = 2.0f;
  for (int it = 0; it < 1000; ++it){
    float sq = 1.0f - 0.0331f*(X*X);
    bool cont = false;
    if (U >= sq){
      float lV  = cr_logf(Vv);
      float rhs = 0.5f*X + ((d - d*Vv) + d*lV);
      cont = (cr_logf(U) >= rhs);
    }
    if (!cont) break;
    TFKey nk = tf_child(key, 0u);
    TFKey xk = tf_child(key, 1u);
    TFKey Uk = tf_child(key, 2u);
    key = nk;
    float x = 0.0f, v = -1.0f;
    for (int j = 0; j < 1000 && v <= 0.0f; ++j){
      TFKey nx = tf_child(xk, 0u);
      TFKey sk = tf_child(xk, 1u);
      xk = nx;
      x = normal_f(sk);
      v = 1.0f + x*c;
    }
    X = x*x;
    Vv = (v*v)*v;
    U = u01(Uk);
  }
  float boost = 1.0f;
  if (!bm) boost = cr_powf(u01(sub), 1.0f / a_orig);
  return (d*Vv)*boost;
}

DEV double digamma_d(double x){
  double r = 0.0;
  while (x < 6.0){ r -= 1.0/x; x += 1.0; }
  double ix = 1.0/x, ix2 = ix*ix;
  double ser = ix2*(1.0/12 - ix2*(1.0/120 - ix2*(1.0/252 - ix2*(1.0/240 - ix2*(1.0/132)))));
  return r + log(x) - 0.5*ix - ser;
}

DEV float softplus_cr(float x){   // jax.nn.softplus = logaddexp(x, 0)
  double xd = (double)x;
  if (x > 0.0f) return (float)(xd + log1p(exp(-xd)));
  return (float)log1p(exp(xd));
}

// ============================ kernels ============================
// K1: pre_part[s][2048][100] partial GEMM  bows[2048,50000] @ W1[50000,100]
// EXACT round-5 structure — the measured best (423 us) across 7 variants:
// single-buffer LDS, 2 barriers/tile, scalar W1 loads, fused staging.
__global__ __launch_bounds__(256) void k1_gemm(const float* __restrict__ bows,
                                               const float* __restrict__ W1,
                                               float* __restrict__ pre_part){
  __shared__ float4 At4[64*20];            // 20 KB
  int rowb = blockIdx.x * 64;
  int kb   = blockIdx.y * 400;
  int tid  = threadIdx.x;
  int c    = tid & 31;
  int r8   = tid >> 5;
  float acc[8][4] = {};
  int cols[4];
  #pragma unroll
  for (int j = 0; j < 4; ++j){ int col = c + 32*j; cols[j] = col < 100 ? col : 96; }
  for (int t = 0; t < 5; ++t){
    int k0 = kb + t*80;
    #pragma unroll
    for (int j = 0; j < 5; ++j){
      int idx = tid + 256*j;
      int r = idx / 20, kf = idx - 20*r;
      At4[idx] = *(const float4*)(bows + (size_t)(rowb + r)*50000 + k0 + kf*4);
    }
    __syncthreads();
    const float* wbase = W1 + (size_t)k0 * 100;
    #pragma unroll 4
    for (int k4 = 0; k4 < 80; k4 += 4){
      float4 a[8];
      #pragma unroll
      for (int i = 0; i < 8; ++i) a[i] = At4[(r8 + 8*i)*20 + (k4 >> 2)];
      #pragma unroll
      for (int kk = 0; kk < 4; ++kk){
        const float* wr = wbase + (size_t)(k4 + kk)*100;
        float w[4];
        #pragma unroll
        for (int j = 0; j < 4; ++j) w[j] = wr[cols[j]];
        #pragma unroll
        for (int i = 0; i < 8; ++i){
          float av = (kk == 0) ? a[i].x : (kk == 1) ? a[i].y : (kk == 2) ? a[i].z : a[i].w;
          #pragma unroll
          for (int j = 0; j < 4; ++j) acc[i][j] = fmaf(av, w[j], acc[i][j]);
        }
      }
    }
    __syncthreads();
  }
  float* pp = pre_part + (size_t)blockIdx.y * 204800;
  #pragma unroll
  for (int i = 0; i < 8; ++i)
    #pragma unroll
    for (int j = 0; j < 4; ++j){
      int col = c + 32*j;
      if (col < 100) pp[(size_t)(rowb + r8 + 8*i)*100 + col] = acc[i][j];
    }
}

// K2a: h1 = softplus(sum_s pre_part + b1)   (125 K-splits, fixed order)
__global__ void k2a(const float* __restrict__ pre_part, const float* __restrict__ b1,
                    float* __restrict__ h1){
  int idx = blockIdx.x*256 + threadIdx.x;      // 204800
  float s = 0.0f;
  #pragma unroll 5
  for (int sp = 0; sp < 125; ++sp) s += pre_part[(size_t)sp*204800 + idx];
  s += b1[idx % 100];
  h1[idx] = softplus_cr(s);
}

// K2b: h2 = softplus(h1 @ W2 + b2)
__global__ void k2b(const float* __restrict__ h1, const float* __restrict__ W2,
                    const float* __restrict__ b2, float* __restrict__ h2){
  int idx = blockIdx.x*256 + threadIdx.x;      // 204800
  int row = idx / 100, c2 = idx - 100*row;
  float acc = 0.0f;
  for (int k = 0; k < 100; ++k) acc = fmaf(h1[row*100 + k], W2[k*100 + c2], acc);
  h2[idx] = softplus_cr(acc + b2[c2]);
}

// K2c: t = h2 @ Wt + bt
__global__ void k2c(const float* __restrict__ h2, const float* __restrict__ Wt,
                    const float* __restrict__ bt, float* __restrict__ tbuf){
  int idx = blockIdx.x*256 + threadIdx.x;      // 102400
  int row = idx / 50, c3 = idx - 50*row;
  float acc = 0.0f;
  for (int k = 0; k < 100; ++k) acc = fmaf(h2[row*100 + k], Wt[k*50 + c3], acc);
  tbuf[idx] = acc + bt[c3];
}

// K3: per-feature batch mean / rsqrt(var+eps)
__global__ void k3_bn(const float* __restrict__ t, float* __restrict__ musig){
  int k = blockIdx.x, tid = threadIdx.x;
  __shared__ float red[256];
  float s = 0.0f;
  for (int r = tid; r < 2048; r += 256) s += t[r*50 + k];
  red[tid] = s; __syncthreads();
  for (int off = 128; off > 0; off >>= 1){ if (tid < off) red[tid] += red[tid+off]; __syncthreads(); }
  float mu = red[0] / 2048.0f;
  __syncthreads();
  float s2 = 0.0f;
  for (int r = tid; r < 2048; r += 256){ float d = t[r*50 + k] - mu; s2 += d*d; }
  red[tid] = s2; __syncthreads();
  for (int off = 128; off > 0; off >>= 1){ if (tid < off) red[tid] += red[tid+off]; __syncthreads(); }
  if (tid == 0){
    float var = red[0] / 2048.0f;
    musig[k] = mu;
    musig[64 + k] = (float)(1.0 / sqrt((double)(var + 1e-5f)));
  }
}

// K4: alpha = exp(BN(t)); g = Gamma(alpha) via JAX-compatible sampler
__global__ void k4_gamma(const float* __restrict__ t, const float* __restrict__ musig,
                         const float* __restrict__ bng, const float* __restrict__ bnb,
                         float* __restrict__ alpha_out, float* __restrict__ g_out){
  #pragma clang fp contract(off)
  int j = blockIdx.x*256 + threadIdx.x;        // 102400
  int row = j / 50, k = j - 50*row; (void)row;
  float mu = musig[k], rs = musig[64 + k];
  float th = ((t[j] - mu) * rs) * bng[k] + bnb[k];
  float alpha = cr_expf(th);
  alpha_out[j] = alpha;
  TFKey master{0u, 42u};                        // jax.random.key(42)
  TFKey ek = tf2x32(master, 0u, (uint32_t)j);   // partitionable split over flat index
  g_out[j] = gamma_one(ek, alpha);
}

// K5: sample = g / rowsum; kld per row
__global__ void k5_row(const float* __restrict__ g, const float* __restrict__ alpha,
                       float* __restrict__ sample, float* __restrict__ kld){
  int lane = threadIdx.x & 63;
  int row = blockIdx.x*4 + (threadIdx.x >> 6);
  int base = row*50;
  float gv = (lane < 50) ? g[base + lane] : 0.0f;
  float av = (lane < 50) ? alpha[base + lane] : 0.0f;
  float sg = gv, a0 = av;
  for (int o = 32; o > 0; o >>= 1){ sg += __shfl_xor(sg, o, 64); a0 += __shfl_xor(a0, o, 64); }
  if (lane < 50) sample[base + lane] = gv / sg;
  double dga0 = digamma_d((double)a0);
  double gl = 0.0, tm = 0.0;
  if (lane < 50){
    double ad = (double)av;
    gl = lgamma(ad);
    tm = (ad - 1.0) * (digamma_d(ad) - dga0);
  }
  for (int o = 32; o > 0; o >>= 1){ gl += __shfl_xor(gl, o, 64); tm += __shfl_xor(tm, o, 64); }
  if (lane == 0)
    kld[row] = (float)(lgamma((double)a0) - gl - lgamma(50.0) + tm);
}

// ---- K6 round 12: z computed ONCE. k6a writes z into the logits buffer and
// accumulates per-row partials lane-locally across 7 col-tiles (one f64
// butterfly per 4-row pass, was per tile). part lives in d_ws (survives the
// z overwrite of the logits-region scratch). k6z = elementwise z - lse.

// K6a: z + partials {sum exp(z), sum z*bow, sum bow} -> part[row][28][3]
__global__ __launch_bounds__(256) void k6a(const float* __restrict__ sample,
                                           const float* __restrict__ Wd,
                                           const float* __restrict__ bd,
                                           const float* __restrict__ bows,
                                           float* __restrict__ zout,
                                           double* __restrict__ part){
  __shared__ float s_lds[64*52];
  int rowb = blockIdx.x * 64;
  int tb0  = blockIdx.y * 7;                   // 7 col-tiles of 256 per block
  int tid = threadIdx.x;
  for (int idx = tid; idx < 64*52; idx += 256){
    int r = idx / 52, k = idx - 52*r;
    s_lds[idx] = (k < 50) ? sample[(size_t)(rowb + r)*50 + k] : 0.0f;
  }
  __syncthreads();
  int lane = tid & 63, w = tid >> 6;
  for (int p = 0; p < 4; ++p){
    int r0 = w*16 + p*4;
    const float* sb = s_lds + r0*52;
    double se_l[4] = {}, s1_l[4] = {}, sb_l[4] = {};
    for (int ct = 0; ct < 7; ++ct){
      int col = (tb0 + ct)*256 + 4*lane;
      if (col < 50000){
        float4 bd4 = *(const float4*)(bd + col);
        float4 acc[4] = {};
        #pragma unroll 5
        for (int k = 0; k < 50; ++k){
          float4 wd4 = *(const float4*)(Wd + (size_t)k*50000 + col);
          #pragma unroll
          for (int r = 0; r < 4; ++r){
            float sv = sb[r*52 + k];
            acc[r].x = fmaf(sv, wd4.x, acc[r].x);
            acc[r].y = fmaf(sv, wd4.y, acc[r].y);
            acc[r].z = fmaf(sv, wd4.z, acc[r].z);
            acc[r].w = fmaf(sv, wd4.w, acc[r].w);
          }
        }
        #pragma unroll
        for (int r = 0; r < 4; ++r){
          float4 bw = *(const float4*)(bows + (size_t)(rowb + r0 + r)*50000 + col);
          float zx = bd4.x + acc[r].x;
          float zy = bd4.y + acc[r].y;
          float zz = bd4.z + acc[r].z;
          float zw = bd4.w + acc[r].w;
          float4 z4; z4.x = zx; z4.y = zy; z4.z = zz; z4.w = zw;
          *(float4*)(zout + (size_t)(rowb + r0 + r)*50000 + col) = z4;
          se_l[r] += ((double)expf(zx) + (double)expf(zy)) + ((double)expf(zz) + (double)expf(zw));
          s1_l[r] += (((double)zx*bw.x + (double)zy*bw.y) + ((double)zz*bw.z + (double)zw*bw.w));
          sb_l[r] += (((double)bw.x + (double)bw.y) + ((double)bw.z + (double)bw.w));
        }
      }
    }
    #pragma unroll
    for (int r = 0; r < 4; ++r){
      double se = se_l[r], s1 = s1_l[r], sbw = sb_l[r];
      for (int o = 32; o > 0; o >>= 1){
        se  += __shfl_xor(se,  o, 64);
        s1  += __shfl_xor(s1,  o, 64);
        sbw += __shfl_xor(sbw, o, 64);
      }
      if (lane == 0){
        size_t off = ((size_t)(rowb + r0 + r)*28 + blockIdx.y)*3;
        part[off] = se; part[off+1] = s1; part[off+2] = sbw;
      }
    }
  }
}

// K6m: reduce partials -> lse, rec_loss
__global__ void k6m(const double* __restrict__ part, float* __restrict__ lse,
                    float* __restrict__ rec){
  int row = blockIdx.x*256 + threadIdx.x;      // 2048
  double se = 0, s1 = 0, sb = 0;
  const double* p = part + (size_t)row*84;     // 28*3
  for (int q = 0; q < 28; ++q){ se += p[3*q]; s1 += p[3*q+1]; sb += p[3*q+2]; }
  double l = log(se);
  lse[row] = (float)l;
  rec[row] = (float)(l*sb - s1);
}

// K6z: in-place logits = z - lse[row]  (float4 grid-stride; 12500 float4/row)
__global__ void k6z(float* __restrict__ logits, const float* __restrict__ lse){
  size_t i = (size_t)blockIdx.x*256 + threadIdx.x;
  const size_t n4 = 25600000;                  // 2048*50000/4
  size_t stride = (size_t)gridDim.x*256;
  for (; i < n4; i += stride){
    int row = (int)(i / 12500);
    float lf = lse[row];
    float4* p = (float4*)logits + i;
    float4 z = *p;
    z.x -= lf; z.y -= lf; z.z -= lf; z.w -= lf;
    *p = z;
  }
}

// ============================ launcher ============================
extern "C" void kernel_launch(void* const* d_in, const int* in_sizes, int n_in,
                              void* d_out, int out_size, void* d_ws, size_t ws_size,
                              hipStream_t stream){
  (void)in_sizes; (void)n_in; (void)out_size; (void)ws_size;
  const float* bows = (const float*)d_in[0];
  const float* W1   = (const float*)d_in[1];
  const float* b1   = (const float*)d_in[2];
  const float* W2   = (const float*)d_in[3];
  const float* b2   = (const float*)d_in[4];
  const float* Wt   = (const float*)d_in[5];
  const float* bt   = (const float*)d_in[6];
  const float* bng  = (const float*)d_in[7];
  const float* bnb  = (const float*)d_in[8];
  const float* Wd   = (const float*)d_in[9];
  const float* bd   = (const float*)d_in[10];

  float* out    = (float*)d_out;
  float* sample = out;                                     // [2048*50]
  float* logits = out + 102400;                            // [2048*50000]
  float* kld    = out + 102400 + (size_t)2048*50000;       // [2048]
  float* rec    = kld + 2048;                              // [2048]

  // Scratch in the logits region — all dead before k6a overwrites it with z.
  float*  pre_part = logits;                               // [125][2048][100]
  float*  h1    = pre_part + (size_t)125*2048*100;         // 204800
  float*  h2    = h1 + 204800;
  float*  tbuf  = h2 + 204800;                             // 102400
  float*  abuf  = tbuf + 102400;
  float*  gbuf  = abuf + 102400;
  float*  musig = gbuf + 102400;                           // 128
  // Live-across-z scratch in d_ws: part [2048][28][3] f64 + lse (1.39 MB).
  double* part  = (double*)d_ws;
  float*  lsew  = (float*)(part + (size_t)2048*28*3);

  k1_gemm<<<dim3(32, 125), 256, 0, stream>>>(bows, W1, pre_part);
  k2a<<<800, 256, 0, stream>>>(pre_part, b1, h1);
  k2b<<<800, 256, 0, stream>>>(h1, W2, b2, h2);
  k2c<<<400, 256, 0, stream>>>(h2, Wt, bt, tbuf);
  k3_bn<<<50, 256, 0, stream>>>(tbuf, musig);
  k4_gamma<<<400, 256, 0, stream>>>(tbuf, musig, bng, bnb, abuf, gbuf);
  k5_row<<<512, 256, 0, stream>>>(gbuf, abuf, sample, kld);
  k6a<<<dim3(32, 28), 256, 0, stream>>>(sample, Wd, bd, bows, logits, part);
  k6m<<<8, 256, 0, stream>>>(part, lsew, rec);
  k6z<<<4096, 256, 0, stream>>>(logits, lsew);
}

// Round 13
// 1040.395 us; speedup vs baseline: 1.2126x; 1.2126x over previous
//
#include <hip/hip_runtime.h>
#include <cstdint>
#include <cstddef>

#define DEV __device__ __forceinline__

// ============================ threefry2x32 (JAX) ============================
struct TFKey { uint32_t a, b; };

DEV uint32_t rotl32(uint32_t x, uint32_t r){ return (x << r) | (x >> (32u - r)); }

DEV TFKey tf2x32(TFKey k, uint32_t x0, uint32_t x1){
  uint32_t ks0 = k.a, ks1 = k.b, ks2 = k.a ^ k.b ^ 0x1BD11BDAu;
  x0 += ks0; x1 += ks1;
  x0 += x1; x1 = rotl32(x1,13); x1 ^= x0;
  x0 += x1; x1 = rotl32(x1,15); x1 ^= x0;
  x0 += x1; x1 = rotl32(x1,26); x1 ^= x0;
  x0 += x1; x1 = rotl32(x1, 6); x1 ^= x0;
  x0 += ks1; x1 += ks2 + 1u;
  x0 += x1; x1 = rotl32(x1,17); x1 ^= x0;
  x0 += x1; x1 = rotl32(x1,29); x1 ^= x0;
  x0 += x1; x1 = rotl32(x1,16); x1 ^= x0;
  x0 += x1; x1 = rotl32(x1,24); x1 ^= x0;
  x0 += ks2; x1 += ks0 + 2u;
  x0 += x1; x1 = rotl32(x1,13); x1 ^= x0;
  x0 += x1; x1 = rotl32(x1,15); x1 ^= x0;
  x0 += x1; x1 = rotl32(x1,26); x1 ^= x0;
  x0 += x1; x1 = rotl32(x1, 6); x1 ^= x0;
  x0 += ks0; x1 += ks1 + 3u;
  x0 += x1; x1 = rotl32(x1,17); x1 ^= x0;
  x0 += x1; x1 = rotl32(x1,29); x1 ^= x0;
  x0 += x1; x1 = rotl32(x1,16); x1 ^= x0;
  x0 += x1; x1 = rotl32(x1,24); x1 ^= x0;
  x0 += ks1; x1 += ks2 + 4u;
  x0 += x1; x1 = rotl32(x1,13); x1 ^= x0;
  x0 += x1; x1 = rotl32(x1,15); x1 ^= x0;
  x0 += x1; x1 = rotl32(x1,26); x1 ^= x0;
  x0 += x1; x1 = rotl32(x1, 6); x1 ^= x0;
  x0 += ks2; x1 += ks0 + 5u;
  return TFKey{x0, x1};
}

// jax_threefry_partitionable = True semantics (default since jax 0.4.36)
DEV TFKey tf_child(TFKey k, uint32_t i){ return tf2x32(k, 0u, i); }
DEV uint32_t rb32(TFKey k){ TFKey o = tf2x32(k, 0u, 0u); return o.a ^ o.b; }

// jax.random.uniform(key, (), f32, 0, 1)
DEV float u01(TFKey k){
  uint32_t bits = rb32(k);
  return __uint_as_float((bits >> 9) | 0x3F800000u) - 1.0f;
}

// correctly-rounded f32 transcendentals via f64 (match glibc CR libm)
DEV float cr_logf(float x){ return (float)log((double)x); }
DEV float cr_expf(float x){ return (float)exp((double)x); }
DEV float cr_powf(float x, float y){ return (float)pow((double)x, (double)y); }

// XLA ErfInv32 (Giles) — exact op order, no FP contraction
DEV float xla_erfinv(float x){
  #pragma clang fp contract(off)
  float w = -(float)log1p((double)(-(x*x)));
  float p;
  if (w < 5.0f){
    w = w - 2.5f;
    p = 2.81022636e-08f;
    p = 3.43273939e-07f + p*w;
    p = -3.5233877e-06f + p*w;
    p = -4.39150654e-06f + p*w;
    p = 0.00021858087f  + p*w;
    p = -0.00125372503f + p*w;
    p = -0.00417768164f + p*w;
    p = 0.246640727f    + p*w;
    p = 1.50140941f     + p*w;
  } else {
    w = sqrtf(w) - 3.0f;
    p = -0.000200214257f;
    p = 0.000100950558f + p*w;
    p = 0.00134934322f  + p*w;
    p = -0.00367342844f + p*w;
    p = 0.00573950773f  + p*w;
    p = -0.0076224613f  + p*w;
    p = 0.00943887047f  + p*w;
    p = 1.00167406f     + p*w;
    p = 2.83297682f     + p*w;
  }
  return p*x;
}

// jax.random.normal: u = uniform(lo=nextafter(-1,0), hi=1); sqrt(2)*erfinv(u)
DEV float normal_f(TFKey k){
  #pragma clang fp contract(off)
  uint32_t bits = rb32(k);
  float f = __uint_as_float((bits >> 9) | 0x3F800000u) - 1.0f;
  const float lo = -0x1.fffffep-1f;      // nextafter(-1, 0)
  float u = f*2.0f + lo;                  // (hi - lo) rounds to exactly 2.0f
  u = fmaxf(lo, u);
  return 0x1.6a09e6p+0f * xla_erfinv(u);  // np.float32(sqrt(2))
}

// jax _gamma_one (Marsaglia–Tsang), log_space=False
DEV float gamma_one(TFKey ek, float alpha){
  #pragma clang fp contract(off)
  TFKey key = tf_child(ek, 0u);
  TFKey sub = tf_child(ek, 1u);
  bool bm = (alpha >= 1.0f);
  float a_orig = alpha;
  float ab = bm ? alpha : (alpha + 1.0f);
  const float c13 = 0x1.555556p-2f;       // float32(1/3)
  float d = ab - c13;
  float c = c13 / sqrtf(d);
  float X = 0.0f, Vv = 1.0f, U = 2.0f;
  for (int it = 0; it < 1000; ++it){
    float sq = 1.0f - 0.0331f*(X*X);
    bool cont = false;
    if (U >= sq){
      float lV  = cr_logf(Vv);
      float rhs = 0.5f*X + ((d - d*Vv) + d*lV);
      cont = (cr_logf(U) >= rhs);
    }
    if (!cont) break;
    TFKey nk = tf_child(key, 0u);
    TFKey xk = tf_child(key, 1u);
    TFKey Uk = tf_child(key, 2u);
    key = nk;
    float x = 0.0f, v = -1.0f;
    for (int j = 0; j < 1000 && v <= 0.0f; ++j){
      TFKey nx = tf_child(xk, 0u);
      TFKey sk = tf_child(xk, 1u);
      xk = nx;
      x = normal_f(sk);
      v = 1.0f + x*c;
    }
    X = x*x;
    Vv = (v*v)*v;
    U = u01(Uk);
  }
  float boost = 1.0f;
  if (!bm) boost = cr_powf(u01(sub), 1.0f / a_orig);
  return (d*Vv)*boost;
}

DEV double digamma_d(double x){
  double r = 0.0;
  while (x < 6.0){ r -= 1.0/x; x += 1.0; }
  double ix = 1.0/x, ix2 = ix*ix;
  double ser = ix2*(1.0/12 - ix2*(1.0/120 - ix2*(1.0/252 - ix2*(1.0/240 - ix2*(1.0/132)))));
  return r + log(x) - 0.5*ix - ser;
}

DEV float softplus_cr(float x){   // jax.nn.softplus = logaddexp(x, 0)
  double xd = (double)x;
  if (x > 0.0f) return (float)(xd + log1p(exp(-xd)));
  return (float)log1p(exp(xd));
}

// ============================ kernels ============================
// K1: pre_part[s][2048][100] partial GEMM  bows[2048,50000] @ W1[50000,100]
// EXACT round-5 structure — the measured best (423 us) across 7 variants.
__global__ __launch_bounds__(256) void k1_gemm(const float* __restrict__ bows,
                                               const float* __restrict__ W1,
                                               float* __restrict__ pre_part){
  __shared__ float4 At4[64*20];            // 20 KB
  int rowb = blockIdx.x * 64;
  int kb   = blockIdx.y * 400;
  int tid  = threadIdx.x;
  int c    = tid & 31;
  int r8   = tid >> 5;
  float acc[8][4] = {};
  int cols[4];
  #pragma unroll
  for (int j = 0; j < 4; ++j){ int col = c + 32*j; cols[j] = col < 100 ? col : 96; }
  for (int t = 0; t < 5; ++t){
    int k0 = kb + t*80;
    #pragma unroll
    for (int j = 0; j < 5; ++j){
      int idx = tid + 256*j;
      int r = idx / 20, kf = idx - 20*r;
      At4[idx] = *(const float4*)(bows + (size_t)(rowb + r)*50000 + k0 + kf*4);
    }
    __syncthreads();
    const float* wbase = W1 + (size_t)k0 * 100;
    #pragma unroll 4
    for (int k4 = 0; k4 < 80; k4 += 4){
      float4 a[8];
      #pragma unroll
      for (int i = 0; i < 8; ++i) a[i] = At4[(r8 + 8*i)*20 + (k4 >> 2)];
      #pragma unroll
      for (int kk = 0; kk < 4; ++kk){
        const float* wr = wbase + (size_t)(k4 + kk)*100;
        float w[4];
        #pragma unroll
        for (int j = 0; j < 4; ++j) w[j] = wr[cols[j]];
        #pragma unroll
        for (int i = 0; i < 8; ++i){
          float av = (kk == 0) ? a[i].x : (kk == 1) ? a[i].y : (kk == 2) ? a[i].z : a[i].w;
          #pragma unroll
          for (int j = 0; j < 4; ++j) acc[i][j] = fmaf(av, w[j], acc[i][j]);
        }
      }
    }
    __syncthreads();
  }
  float* pp = pre_part + (size_t)blockIdx.y * 204800;
  #pragma unroll
  for (int i = 0; i < 8; ++i)
    #pragma unroll
    for (int j = 0; j < 4; ++j){
      int col = c + 32*j;
      if (col < 100) pp[(size_t)(rowb + r8 + 8*i)*100 + col] = acc[i][j];
    }
}

// K2a: h1 = softplus(sum_s pre_part + b1)   (125 K-splits, fixed order)
__global__ void k2a(const float* __restrict__ pre_part, const float* __restrict__ b1,
                    float* __restrict__ h1){
  int idx = blockIdx.x*256 + threadIdx.x;      // 204800
  float s = 0.0f;
  #pragma unroll 5
  for (int sp = 0; sp < 125; ++sp) s += pre_part[(size_t)sp*204800 + idx];
  s += b1[idx % 100];
  h1[idx] = softplus_cr(s);
}

// K2b: h2 = softplus(h1 @ W2 + b2)
__global__ void k2b(const float* __restrict__ h1, const float* __restrict__ W2,
                    const float* __restrict__ b2, float* __restrict__ h2){
  int idx = blockIdx.x*256 + threadIdx.x;      // 204800
  int row = idx / 100, c2 = idx - 100*row;
  float acc = 0.0f;
  for (int k = 0; k < 100; ++k) acc = fmaf(h1[row*100 + k], W2[k*100 + c2], acc);
  h2[idx] = softplus_cr(acc + b2[c2]);
}

// K2c: t = h2 @ Wt + bt
__global__ void k2c(const float* __restrict__ h2, const float* __restrict__ Wt,
                    const float* __restrict__ bt, float* __restrict__ tbuf){
  int idx = blockIdx.x*256 + threadIdx.x;      // 102400
  int row = idx / 50, c3 = idx - 50*row;
  float acc = 0.0f;
  for (int k = 0; k < 100; ++k) acc = fmaf(h2[row*100 + k], Wt[k*50 + c3], acc);
  tbuf[idx] = acc + bt[c3];
}

// K3: per-feature batch mean / rsqrt(var+eps)
__global__ void k3_bn(const float* __restrict__ t, float* __restrict__ musig){
  int k = blockIdx.x, tid = threadIdx.x;
  __shared__ float red[256];
  float s = 0.0f;
  for (int r = tid; r < 2048; r += 256) s += t[r*50 + k];
  red[tid] = s; __syncthreads();
  for (int off = 128; off > 0; off >>= 1){ if (tid < off) red[tid] += red[tid+off]; __syncthreads(); }
  float mu = red[0] / 2048.0f;
  __syncthreads();
  float s2 = 0.0f;
  for (int r = tid; r < 2048; r += 256){ float d = t[r*50 + k] - mu; s2 += d*d; }
  red[tid] = s2; __syncthreads();
  for (int off = 128; off > 0; off >>= 1){ if (tid < off) red[tid] += red[tid+off]; __syncthreads(); }
  if (tid == 0){
    float var = red[0] / 2048.0f;
    musig[k] = mu;
    musig[64 + k] = (float)(1.0 / sqrt((double)(var + 1e-5f)));
  }
}

// K4: alpha = exp(BN(t)); g = Gamma(alpha) via JAX-compatible sampler
__global__ void k4_gamma(const float* __restrict__ t, const float* __restrict__ musig,
                         const float* __restrict__ bng, const float* __restrict__ bnb,
                         float* __restrict__ alpha_out, float* __restrict__ g_out){
  #pragma clang fp contract(off)
  int j = blockIdx.x*256 + threadIdx.x;        // 102400
  int row = j / 50, k = j - 50*row; (void)row;
  float mu = musig[k], rs = musig[64 + k];
  float th = ((t[j] - mu) * rs) * bng[k] + bnb[k];
  float alpha = cr_expf(th);
  alpha_out[j] = alpha;
  TFKey master{0u, 42u};                        // jax.random.key(42)
  TFKey ek = tf2x32(master, 0u, (uint32_t)j);   // partitionable split over flat index
  g_out[j] = gamma_one(ek, alpha);
}

// K5: sample = g / rowsum; kld per row
__global__ void k5_row(const float* __restrict__ g, const float* __restrict__ alpha,
                       float* __restrict__ sample, float* __restrict__ kld){
  int lane = threadIdx.x & 63;
  int row = blockIdx.x*4 + (threadIdx.x >> 6);
  int base = row*50;
  float gv = (lane < 50) ? g[base + lane] : 0.0f;
  float av = (lane < 50) ? alpha[base + lane] : 0.0f;
  float sg = gv, a0 = av;
  for (int o = 32; o > 0; o >>= 1){ sg += __shfl_xor(sg, o, 64); a0 += __shfl_xor(a0, o, 64); }
  if (lane < 50) sample[base + lane] = gv / sg;
  double dga0 = digamma_d((double)a0);
  double gl = 0.0, tm = 0.0;
  if (lane < 50){
    double ad = (double)av;
    gl = lgamma(ad);
    tm = (ad - 1.0) * (digamma_d(ad) - dga0);
  }
  for (int o = 32; o > 0; o >>= 1){ gl += __shfl_xor(gl, o, 64); tm += __shfl_xor(tm, o, 64); }
  if (lane == 0)
    kld[row] = (float)(lgamma((double)a0) - gl - lgamma(50.0) + tm);
}

// ---- K6 round 13: z computed ONCE with the proven per-tile grid (32,196).
// k6a_f = R5 k6a body + coalesced z-store into logits + f32 per-tile partials
// in d_ws. k6z = elementwise z - lse. Runtime ws_size guard falls back to the
// R5 split path (k6a_sep + k6b) if d_ws is too small.

// K6a fused: z + partials -> partF[row][196][3] (f32)
__global__ __launch_bounds__(256) void k6a_f(const float* __restrict__ sample,
                                             const float* __restrict__ Wd,
                                             const float* __restrict__ bd,
                                             const float* __restrict__ bows,
                                             float* __restrict__ zout,
                                             float* __restrict__ partF){
  __shared__ float s_lds[64*52];
  int rowb = blockIdx.x * 64;
  int colb = blockIdx.y * 256;
  int tid = threadIdx.x;
  for (int idx = tid; idx < 64*52; idx += 256){
    int r = idx / 52, k = idx - 52*r;
    s_lds[idx] = (k < 50) ? sample[(size_t)(rowb + r)*50 + k] : 0.0f;
  }
  __syncthreads();
  int lane = tid & 63, w = tid >> 6;
  int col = colb + 4*lane;
  bool act = col < 50000;
  float4 bd4 = {0.0f, 0.0f, 0.0f, 0.0f};
  if (act) bd4 = *(const float4*)(bd + col);
  for (int p = 0; p < 4; ++p){
    int r0 = w*16 + p*4;
    float4 acc[4] = {};
    const float* sb = s_lds + r0*52;
    if (act){
      #pragma unroll
      for (int q = 0; q < 12; ++q){
        #pragma unroll
        for (int kk = 0; kk < 4; ++kk){
          int k = q*4 + kk;
          float4 wd4 = *(const float4*)(Wd + (size_t)k*50000 + col);
          #pragma unroll
          for (int r = 0; r < 4; ++r){
            float sv = sb[r*52 + k];
            acc[r].x = fmaf(sv, wd4.x, acc[r].x);
            acc[r].y = fmaf(sv, wd4.y, acc[r].y);
            acc[r].z = fmaf(sv, wd4.z, acc[r].z);
            acc[r].w = fmaf(sv, wd4.w, acc[r].w);
          }
        }
      }
      #pragma unroll
      for (int kk = 0; kk < 2; ++kk){
        int k = 48 + kk;
        float4 wd4 = *(const float4*)(Wd + (size_t)k*50000 + col);
        #pragma unroll
        for (int r = 0; r < 4; ++r){
          float sv = sb[r*52 + k];
          acc[r].x = fmaf(sv, wd4.x, acc[r].x);
          acc[r].y = fmaf(sv, wd4.y, acc[r].y);
          acc[r].z = fmaf(sv, wd4.z, acc[r].z);
          acc[r].w = fmaf(sv, wd4.w, acc[r].w);
        }
      }
    }
    #pragma unroll
    for (int r = 0; r < 4; ++r){
      double se = 0.0, s1 = 0.0, sbw = 0.0;
      if (act){
        float4 bw = *(const float4*)(bows + (size_t)(rowb + r0 + r)*50000 + col);
        float zx = bd4.x + acc[r].x;
        float zy = bd4.y + acc[r].y;
        float zz = bd4.z + acc[r].z;
        float zw = bd4.w + acc[r].w;
        float4 z4; z4.x = zx; z4.y = zy; z4.z = zz; z4.w = zw;
        *(float4*)(zout + (size_t)(rowb + r0 + r)*50000 + col) = z4;
        se  = ((double)expf(zx) + (double)expf(zy)) + ((double)expf(zz) + (double)expf(zw));
        s1  = (((double)zx*bw.x + (double)zy*bw.y) + ((double)zz*bw.z + (double)zw*bw.w));
        sbw = (((double)bw.x + (double)bw.y) + ((double)bw.z + (double)bw.w));
      }
      for (int o = 32; o > 0; o >>= 1){
        se  += __shfl_xor(se,  o, 64);
        s1  += __shfl_xor(s1,  o, 64);
        sbw += __shfl_xor(sbw, o, 64);
      }
      if (lane == 0){
        size_t off = ((size_t)(rowb + r0 + r)*196 + blockIdx.y)*3;
        partF[off] = (float)se; partF[off+1] = (float)s1; partF[off+2] = (float)sbw;
      }
    }
  }
}

// K6m (f32 partials): reduce -> lse, rec
__global__ void k6m_f(const float* __restrict__ partF, float* __restrict__ lse,
                      float* __restrict__ rec){
  int row = blockIdx.x*256 + threadIdx.x;      // 2048
  double se = 0, s1 = 0, sb = 0;
  const float* p = partF + (size_t)row*588;    // 196*3
  for (int q = 0; q < 196; ++q){ se += (double)p[3*q]; s1 += (double)p[3*q+1]; sb += (double)p[3*q+2]; }
  double l = log(se);
  lse[row] = (float)l;
  rec[row] = (float)(l*sb - s1);
}

// K6z: in-place logits = z - lse[row]; grid (49, 2048), 1 float4/thread
__global__ void k6z(float* __restrict__ logits, const float* __restrict__ lse){
  int row = blockIdx.y;
  int col4 = blockIdx.x*256 + threadIdx.x;     // 12500 float4 per row
  if (col4 < 12500){
    float lf = lse[row];
    float4* p = (float4*)(logits + (size_t)row*50000) + col4;
    float4 z = *p;
    z.x -= lf; z.y -= lf; z.z -= lf; z.w -= lf;
    *p = z;
  }
}

// ---- Fallback path (ws too small): exact R5/R11 split kernels, f64 partials
// in the logits-region scratch (k6b recomputes z and overwrites).
__global__ __launch_bounds__(256) void k6a_sep(const float* __restrict__ sample,
                                               const float* __restrict__ Wd,
                                               const float* __restrict__ bd,
                                               const float* __restrict__ bows,
                                               double* __restrict__ part){
  __shared__ float s_lds[64*52];
  int rowb = blockIdx.x * 64;
  int colb = blockIdx.y * 256;
  int tid = threadIdx.x;
  for (int idx = tid; idx < 64*52; idx += 256){
    int r = idx / 52, k = idx - 52*r;
    s_lds[idx] = (k < 50) ? sample[(size_t)(rowb + r)*50 + k] : 0.0f;
  }
  __syncthreads();
  int lane = tid & 63, w = tid >> 6;
  int col = colb + 4*lane;
  bool act = col < 50000;
  float4 bd4 = {0.0f, 0.0f, 0.0f, 0.0f};
  if (act) bd4 = *(const float4*)(bd + col);
  for (int p = 0; p < 4; ++p){
    int r0 = w*16 + p*4;
    float4 acc[4] = {};
    const float* sb = s_lds + r0*52;
    if (act){
      #pragma unroll
      for (int q = 0; q < 12; ++q){
        #pragma unroll
        for (int kk = 0; kk < 4; ++kk){
          int k = q*4 + kk;
          float4 wd4 = *(const float4*)(Wd + (size_t)k*50000 + col);
          #pragma unroll
          for (int r = 0; r < 4; ++r){
            float sv = sb[r*52 + k];
            acc[r].x = fmaf(sv, wd4.x, acc[r].x);
            acc[r].y = fmaf(sv, wd4.y, acc[r].y);
            acc[r].z = fmaf(sv, wd4.z, acc[r].z);
            acc[r].w = fmaf(sv, wd4.w, acc[r].w);
          }
        }
      }
      #pragma unroll
      for (int kk = 0; kk < 2; ++kk){
        int k = 48 + kk;
        float4 wd4 = *(const float4*)(Wd + (size_t)k*50000 + col);
        #pragma unroll
        for (int r = 0; r < 4; ++r){
          float sv = sb[r*52 + k];
          acc[r].x = fmaf(sv, wd4.x, acc[r].x);
          acc[r].y = fmaf(sv, wd4.y, acc[r].y);
          acc[r].z = fmaf(sv, wd4.z, acc[r].z);
          acc[r].w = fmaf(sv, wd4.w, acc[r].w);
        }
      }
    }
    #pragma unroll
    for (int r = 0; r < 4; ++r){
      double se = 0.0, s1 = 0.0, sbw = 0.0;
      if (act){
        float4 bw = *(const float4*)(bows + (size_t)(rowb + r0 + r)*50000 + col);
        float zx = bd4.x + acc[r].x;
        float zy = bd4.y + acc[r].y;
        float zz = bd4.z + acc[r].z;
        float zw = bd4.w + acc[r].w;
        se  = ((double)expf(zx) + (double)expf(zy)) + ((double)expf(zz) + (double)expf(zw));
        s1  = (((double)zx*bw.x + (double)zy*bw.y) + ((double)zz*bw.z + (double)zw*bw.w));
        sbw = (((double)bw.x + (double)bw.y) + ((double)bw.z + (double)bw.w));
      }
      for (int o = 32; o > 0; o >>= 1){
        se  += __shfl_xor(se,  o, 64);
        s1  += __shfl_xor(s1,  o, 64);
        sbw += __shfl_xor(sbw, o, 64);
      }
      if (lane == 0){
        size_t off = ((size_t)(rowb + r0 + r)*196 + blockIdx.y)*3;
        part[off] = se; part[off+1] = s1; part[off+2] = sbw;
      }
    }
  }
}

__global__ void k6m_d(const double* __restrict__ part, float* __restrict__ lse,
                      float* __restrict__ rec){
  int row = blockIdx.x*256 + threadIdx.x;      // 2048
  double se = 0, s1 = 0, sb = 0;
  const double* p = part + (size_t)row*588;    // 196*3
  for (int q = 0; q < 196; ++q){ se += p[3*q]; s1 += p[3*q+1]; sb += p[3*q+2]; }
  double l = log(se);
  lse[row] = (float)l;
  rec[row] = (float)(l*sb - s1);
}

__global__ __launch_bounds__(256) void k6b_sep(const float* __restrict__ sample,
                                               const float* __restrict__ Wd,
                                               const float* __restrict__ bd,
                                               const float* __restrict__ lse,
                                               float* __restrict__ logits){
  __shared__ float s_lds[64*52];
  int rowb = blockIdx.x * 64;
  int colb = blockIdx.y * 256;
  int tid = threadIdx.x;
  for (int idx = tid; idx < 64*52; idx += 256){
    int r = idx / 52, k = idx - 52*r;
    s_lds[idx] = (k < 50) ? sample[(size_t)(rowb + r)*50 + k] : 0.0f;
  }
  __syncthreads();
  int lane = tid & 63, w = tid >> 6;
  int col = colb + 4*lane;
  bool act = col < 50000;
  float4 bd4 = {0.0f, 0.0f, 0.0f, 0.0f};
  if (act) bd4 = *(const float4*)(bd + col);
  for (int p = 0; p < 4; ++p){
    int r0 = w*16 + p*4;
    float4 acc[4] = {};
    const float* sb = s_lds + r0*52;
    if (act){
      #pragma unroll
      for (int q = 0; q < 12; ++q){
        #pragma unroll
        for (int kk = 0; kk < 4; ++kk){
          int k = q*4 + kk;
          float4 wd4 = *(const float4*)(Wd + (size_t)k*50000 + col);
          #pragma unroll
          for (int r = 0; r < 4; ++r){
            float sv = sb[r*52 + k];
            acc[r].x = fmaf(sv, wd4.x, acc[r].x);
            acc[r].y = fmaf(sv, wd4.y, acc[r].y);
            acc[r].z = fmaf(sv, wd4.z, acc[r].z);
            acc[r].w = fmaf(sv, wd4.w, acc[r].w);
          }
        }
      }
      #pragma unroll
      for (int kk = 0; kk < 2; ++kk){
        int k = 48 + kk;
        float4 wd4 = *(const float4*)(Wd + (size_t)k*50000 + col);
        #pragma unroll
        for (int r = 0; r < 4; ++r){
          float sv = sb[r*52 + k];
          acc[r].x = fmaf(sv, wd4.x, acc[r].x);
          acc[r].y = fmaf(sv, wd4.y, acc[r].y);
          acc[r].z = fmaf(sv, wd4.z, acc[r].z);
          acc[r].w = fmaf(sv, wd4.w, acc[r].w);
        }
      }
      #pragma unroll
      for (int r = 0; r < 4; ++r){
        float lf = lse[rowb + r0 + r];
        float4 z;
        z.x = (bd4.x + acc[r].x) - lf;
        z.y = (bd4.y + acc[r].y) - lf;
        z.z = (bd4.z + acc[r].z) - lf;
        z.w = (bd4.w + acc[r].w) - lf;
        *(float4*)(logits + (size_t)(rowb + r0 + r)*50000 + col) = z;
      }
    }
  }
}

// ============================ launcher ============================
extern "C" void kernel_launch(void* const* d_in, const int* in_sizes, int n_in,
                              void* d_out, int out_size, void* d_ws, size_t ws_size,
                              hipStream_t stream){
  (void)in_sizes; (void)n_in; (void)out_size;
  const float* bows = (const float*)d_in[0];
  const float* W1   = (const float*)d_in[1];
  const float* b1   = (const float*)d_in[2];
  const float* W2   = (const float*)d_in[3];
  const float* b2   = (const float*)d_in[4];
  const float* Wt   = (const float*)d_in[5];
  const float* bt   = (const float*)d_in[6];
  const float* bng  = (const float*)d_in[7];
  const float* bnb  = (const float*)d_in[8];
  const float* Wd   = (const float*)d_in[9];
  const float* bd   = (const float*)d_in[10];

  float* out    = (float*)d_out;
  float* sample = out;                                     // [2048*50]
  float* logits = out + 102400;                            // [2048*50000]
  float* kld    = out + 102400 + (size_t)2048*50000;       // [2048]
  float* rec    = kld + 2048;                              // [2048]

  // Scratch in the logits region — dead before k6 writes z/logits there.
  float*  pre_part = logits;                               // [125][2048][100]
  float*  h1    = pre_part + (size_t)125*2048*100;         // 204800
  float*  h2    = h1 + 204800;
  float*  tbuf  = h2 + 204800;                             // 102400
  float*  abuf  = tbuf + 102400;
  float*  gbuf  = abuf + 102400;
  float*  musig = gbuf + 102400;                           // 128

  k1_gemm<<<dim3(32, 125), 256, 0, stream>>>(bows, W1, pre_part);
  k2a<<<800, 256, 0, stream>>>(pre_part, b1, h1);
  k2b<<<800, 256, 0, stream>>>(h1, W2, b2, h2);
  k2c<<<400, 256, 0, stream>>>(h2, Wt, bt, tbuf);
  k3_bn<<<50, 256, 0, stream>>>(tbuf, musig);
  k4_gamma<<<400, 256, 0, stream>>>(tbuf, musig, bng, bnb, abuf, gbuf);
  k5_row<<<512, 256, 0, stream>>>(gbuf, abuf, sample, kld);

  const size_t needF = (size_t)2048*196*3*sizeof(float) + 2048*sizeof(float);
  if (ws_size >= needF){
    // Fused path: z once (written into logits), f32 partials in d_ws.
    float* partF = (float*)d_ws;                 // [2048][196][3] f32
    float* lsew  = partF + (size_t)2048*196*3;   // 2048 f32
    k6a_f<<<dim3(32, 196), 256, 0, stream>>>(sample, Wd, bd, bows, logits, partF);
    k6m_f<<<8, 256, 0, stream>>>(partF, lsew, rec);
    k6z<<<dim3(49, 2048), 256, 0, stream>>>(logits, lsew);
  } else {
    // Fallback: proven R5 split path; f64 partials in logits-region scratch.
    double* partD = (double*)(musig + 128);      // [2048][196][3] f64
    float*  lsew  = (float*)d_ws;                // 2048 f32
    k6a_sep<<<dim3(32, 196), 256, 0, stream>>>(sample, Wd, bd, bows, partD);
    k6m_d<<<8, 256, 0, stream>>>(partD, lsew, rec);
    k6b_sep<<<dim3(32, 196), 256, 0, stream>>>(sample, Wd, bd, lsew, logits);
  }
}

// Round 14
// 976.185 us; speedup vs baseline: 1.2924x; 1.0658x over previous
//
#include <hip/hip_runtime.h>
#include <cstdint>
#include <cstddef>

#define DEV __device__ __forceinline__

// ============================ threefry2x32 (JAX) ============================
struct TFKey { uint32_t a, b; };

DEV uint32_t rotl32(uint32_t x, uint32_t r){ return (x << r) | (x >> (32u - r)); }

DEV TFKey tf2x32(TFKey k, uint32_t x0, uint32_t x1){
  uint32_t ks0 = k.a, ks1 = k.b, ks2 = k.a ^ k.b ^ 0x1BD11BDAu;
  x0 += ks0; x1 += ks1;
  x0 += x1; x1 = rotl32(x1,13); x1 ^= x0;
  x0 += x1; x1 = rotl32(x1,15); x1 ^= x0;
  x0 += x1; x1 = rotl32(x1,26); x1 ^= x0;
  x0 += x1; x1 = rotl32(x1, 6); x1 ^= x0;
  x0 += ks1; x1 += ks2 + 1u;
  x0 += x1; x1 = rotl32(x1,17); x1 ^= x0;
  x0 += x1; x1 = rotl32(x1,29); x1 ^= x0;
  x0 += x1; x1 = rotl32(x1,16); x1 ^= x0;
  x0 += x1; x1 = rotl32(x1,24); x1 ^= x0;
  x0 += ks2; x1 += ks0 + 2u;
  x0 += x1; x1 = rotl32(x1,13); x1 ^= x0;
  x0 += x1; x1 = rotl32(x1,15); x1 ^= x0;
  x0 += x1; x1 = rotl32(x1,26); x1 ^= x0;
  x0 += x1; x1 = rotl32(x1, 6); x1 ^= x0;
  x0 += ks0; x1 += ks1 + 3u;
  x0 += x1; x1 = rotl32(x1,17); x1 ^= x0;
  x0 += x1; x1 = rotl32(x1,29); x1 ^= x0;
  x0 += x1; x1 = rotl32(x1,16); x1 ^= x0;
  x0 += x1; x1 = rotl32(x1,24); x1 ^= x0;
  x0 += ks1; x1 += ks2 + 4u;
  x0 += x1; x1 = rotl32(x1,13); x1 ^= x0;
  x0 += x1; x1 = rotl32(x1,15); x1 ^= x0;
  x0 += x1; x1 = rotl32(x1,26); x1 ^= x0;
  x0 += x1; x1 = rotl32(x1, 6); x1 ^= x0;
  x0 += ks2; x1 += ks0 + 5u;
  return TFKey{x0, x1};
}

// jax_threefry_partitionable = True semantics (default since jax 0.4.36)
DEV TFKey tf_child(TFKey k, uint32_t i){ return tf2x32(k, 0u, i); }
DEV uint32_t rb32(TFKey k){ TFKey o = tf2x32(k, 0u, 0u); return o.a ^ o.b; }

// jax.random.uniform(key, (), f32, 0, 1)
DEV float u01(TFKey k){
  uint32_t bits = rb32(k);
  return __uint_as_float((bits >> 9) | 0x3F800000u) - 1.0f;
}

// correctly-rounded f32 transcendentals via f64 (match glibc CR libm)
DEV float cr_logf(float x){ return (float)log((double)x); }
DEV float cr_expf(float x){ return (float)exp((double)x); }
DEV float cr_powf(float x, float y){ return (float)pow((double)x, (double)y); }

// XLA ErfInv32 (Giles) — exact op order, no FP contraction
DEV float xla_erfinv(float x){
  #pragma clang fp contract(off)
  float w = -(float)log1p((double)(-(x*x)));
  float p;
  if (w < 5.0f){
    w = w - 2.5f;
    p = 2.81022636e-08f;
    p = 3.43273939e-07f + p*w;
    p = -3.5233877e-06f + p*w;
    p = -4.39150654e-06f + p*w;
    p = 0.00021858087f  + p*w;
    p = -0.00125372503f + p*w;
    p = -0.00417768164f + p*w;
    p = 0.246640727f    + p*w;
    p = 1.50140941f     + p*w;
  } else {
    w = sqrtf(w) - 3.0f;
    p = -0.000200214257f;
    p = 0.000100950558f + p*w;
    p = 0.00134934322f  + p*w;
    p = -0.00367342844f + p*w;
    p = 0.00573950773f  + p*w;
    p = -0.0076224613f  + p*w;
    p = 0.00943887047f  + p*w;
    p = 1.00167406f     + p*w;
    p = 2.83297682f     + p*w;
  }
  return p*x;
}

// jax.random.normal: u = uniform(lo=nextafter(-1,0), hi=1); sqrt(2)*erfinv(u)
DEV float normal_f(TFKey k){
  #pragma clang fp contract(off)
  uint32_t bits = rb32(k);
  float f = __uint_as_float((bits >> 9) | 0x3F800000u) - 1.0f;
  const float lo = -0x1.fffffep-1f;      // nextafter(-1, 0)
  float u = f*2.0f + lo;                  // (hi - lo) rounds to exactly 2.0f
  u = fmaxf(lo, u);
  return 0x1.6a09e6p+0f * xla_erfinv(u);  // np.float32(sqrt(2))
}

// jax _gamma_one (Marsaglia–Tsang), log_space=False
DEV float gamma_one(TFKey ek, float alpha){
  #pragma clang fp contract(off)
  TFKey key = tf_child(ek, 0u);
  TFKey sub = tf_child(ek, 1u);
  bool bm = (alpha >= 1.0f);
  float a_orig = alpha;
  float ab = bm ? alpha : (alpha + 1.0f);
  const float c13 = 0x1.555556p-2f;       // float32(1/3)
  float d = ab - c13;
  float c = c13 / sqrtf(d);
  float X = 0.0f, Vv = 1.0f, U = 2.0f;
  for (int it = 0; it < 1000; ++it){
    float sq = 1.0f - 0.0331f*(X*X);
    bool cont = false;
    if (U >= sq){
      float lV  = cr_logf(Vv);
      float rhs = 0.5f*X + ((d - d*Vv) + d*lV);
      cont = (cr_logf(U) >= rhs);
    }
    if (!cont) break;
    TFKey nk = tf_child(key, 0u);
    TFKey xk = tf_child(key, 1u);
    TFKey Uk = tf_child(key, 2u);
    key = nk;
    float x = 0.0f, v = -1.0f;
    for (int j = 0; j < 1000 && v <= 0.0f; ++j){
      TFKey nx = tf_child(xk, 0u);
      TFKey sk = tf_child(xk, 1u);
      xk = nx;
      x = normal_f(sk);
      v = 1.0f + x*c;
    }
    X = x*x;
    Vv = (v*v)*v;
    U = u01(Uk);
  }
  float boost = 1.0f;
  if (!bm) boost = cr_powf(u01(sub), 1.0f / a_orig);
  return (d*Vv)*boost;
}

DEV double digamma_d(double x){
  double r = 0.0;
  while (x < 6.0){ r -= 1.0/x; x += 1.0; }
  double ix = 1.0/x, ix2 = ix*ix;
  double ser = ix2*(1.0/12 - ix2*(1.0/120 - ix2*(1.0/252 - ix2*(1.0/240 - ix2*(1.0/132)))));
  return r + log(x) - 0.5*ix - ser;
}

DEV float softplus_cr(float x){   // jax.nn.softplus = logaddexp(x, 0)
  double xd = (double)x;
  if (x > 0.0f) return (float)(xd + log1p(exp(-xd)));
  return (float)log1p(exp(xd));
}

// ============================ kernels ============================
// K1: pre_part[s][2048][100] partial GEMM  bows[2048,50000] @ W1[50000,100]
// EXACT round-5 structure — the measured best (423 us) across 7 variants.
__global__ __launch_bounds__(256) void k1_gemm(const float* __restrict__ bows,
                                               const float* __restrict__ W1,
                                               float* __restrict__ pre_part){
  __shared__ float4 At4[64*20];            // 20 KB
  int rowb = blockIdx.x * 64;
  int kb   = blockIdx.y * 400;
  int tid  = threadIdx.x;
  int c    = tid & 31;
  int r8   = tid >> 5;
  float acc[8][4] = {};
  int cols[4];
  #pragma unroll
  for (int j = 0; j < 4; ++j){ int col = c + 32*j; cols[j] = col < 100 ? col : 96; }
  for (int t = 0; t < 5; ++t){
    int k0 = kb + t*80;
    #pragma unroll
    for (int j = 0; j < 5; ++j){
      int idx = tid + 256*j;
      int r = idx / 20, kf = idx - 20*r;
      At4[idx] = *(const float4*)(bows + (size_t)(rowb + r)*50000 + k0 + kf*4);
    }
    __syncthreads();
    const float* wbase = W1 + (size_t)k0 * 100;
    #pragma unroll 4
    for (int k4 = 0; k4 < 80; k4 += 4){
      float4 a[8];
      #pragma unroll
      for (int i = 0; i < 8; ++i) a[i] = At4[(r8 + 8*i)*20 + (k4 >> 2)];
      #pragma unroll
      for (int kk = 0; kk < 4; ++kk){
        const float* wr = wbase + (size_t)(k4 + kk)*100;
        float w[4];
        #pragma unroll
        for (int j = 0; j < 4; ++j) w[j] = wr[cols[j]];
        #pragma unroll
        for (int i = 0; i < 8; ++i){
          float av = (kk == 0) ? a[i].x : (kk == 1) ? a[i].y : (kk == 2) ? a[i].z : a[i].w;
          #pragma unroll
          for (int j = 0; j < 4; ++j) acc[i][j] = fmaf(av, w[j], acc[i][j]);
        }
      }
    }
    __syncthreads();
  }
  float* pp = pre_part + (size_t)blockIdx.y * 204800;
  #pragma unroll
  for (int i = 0; i < 8; ++i)
    #pragma unroll
    for (int j = 0; j < 4; ++j){
      int col = c + 32*j;
      if (col < 100) pp[(size_t)(rowb + r8 + 8*i)*100 + col] = acc[i][j];
    }
}

// K2a: h1 = softplus(sum_s pre_part + b1)   (125 K-splits, fixed order)
__global__ void k2a(const float* __restrict__ pre_part, const float* __restrict__ b1,
                    float* __restrict__ h1){
  int idx = blockIdx.x*256 + threadIdx.x;      // 204800
  float s = 0.0f;
  #pragma unroll 5
  for (int sp = 0; sp < 125; ++sp) s += pre_part[(size_t)sp*204800 + idx];
  s += b1[idx % 100];
  h1[idx] = softplus_cr(s);
}

// K2b: h2 = softplus(h1 @ W2 + b2)
__global__ void k2b(const float* __restrict__ h1, const float* __restrict__ W2,
                    const float* __restrict__ b2, float* __restrict__ h2){
  int idx = blockIdx.x*256 + threadIdx.x;      // 204800
  int row = idx / 100, c2 = idx - 100*row;
  float acc = 0.0f;
  for (int k = 0; k < 100; ++k) acc = fmaf(h1[row*100 + k], W2[k*100 + c2], acc);
  h2[idx] = softplus_cr(acc + b2[c2]);
}

// K2c: t = h2 @ Wt + bt
__global__ void k2c(const float* __restrict__ h2, const float* __restrict__ Wt,
                    const float* __restrict__ bt, float* __restrict__ tbuf){
  int idx = blockIdx.x*256 + threadIdx.x;      // 102400
  int row = idx / 50, c3 = idx - 50*row;
  float acc = 0.0f;
  for (int k = 0; k < 100; ++k) acc = fmaf(h2[row*100 + k], Wt[k*50 + c3], acc);
  tbuf[idx] = acc + bt[c3];
}

// K3: per-feature batch mean / rsqrt(var+eps)
__global__ void k3_bn(const float* __restrict__ t, float* __restrict__ musig){
  int k = blockIdx.x, tid = threadIdx.x;
  __shared__ float red[256];
  float s = 0.0f;
  for (int r = tid; r < 2048; r += 256) s += t[r*50 + k];
  red[tid] = s; __syncthreads();
  for (int off = 128; off > 0; off >>= 1){ if (tid < off) red[tid] += red[tid+off]; __syncthreads(); }
  float mu = red[0] / 2048.0f;
  __syncthreads();
  float s2 = 0.0f;
  for (int r = tid; r < 2048; r += 256){ float d = t[r*50 + k] - mu; s2 += d*d; }
  red[tid] = s2; __syncthreads();
  for (int off = 128; off > 0; off >>= 1){ if (tid < off) red[tid] += red[tid+off]; __syncthreads(); }
  if (tid == 0){
    float var = red[0] / 2048.0f;
    musig[k] = mu;
    musig[64 + k] = (float)(1.0 / sqrt((double)(var + 1e-5f)));
  }
}

// K4: alpha = exp(BN(t)); g = Gamma(alpha) via JAX-compatible sampler
__global__ void k4_gamma(const float* __restrict__ t, const float* __restrict__ musig,
                         const float* __restrict__ bng, const float* __restrict__ bnb,
                         float* __restrict__ alpha_out, float* __restrict__ g_out){
  #pragma clang fp contract(off)
  int j = blockIdx.x*256 + threadIdx.x;        // 102400
  int row = j / 50, k = j - 50*row; (void)row;
  float mu = musig[k], rs = musig[64 + k];
  float th = ((t[j] - mu) * rs) * bng[k] + bnb[k];
  float alpha = cr_expf(th);
  alpha_out[j] = alpha;
  TFKey master{0u, 42u};                        // jax.random.key(42)
  TFKey ek = tf2x32(master, 0u, (uint32_t)j);   // partitionable split over flat index
  g_out[j] = gamma_one(ek, alpha);
}

// K5: sample = g / rowsum; kld per row
__global__ void k5_row(const float* __restrict__ g, const float* __restrict__ alpha,
                       float* __restrict__ sample, float* __restrict__ kld){
  int lane = threadIdx.x & 63;
  int row = blockIdx.x*4 + (threadIdx.x >> 6);
  int base = row*50;
  float gv = (lane < 50) ? g[base + lane] : 0.0f;
  float av = (lane < 50) ? alpha[base + lane] : 0.0f;
  float sg = gv, a0 = av;
  for (int o = 32; o > 0; o >>= 1){ sg += __shfl_xor(sg, o, 64); a0 += __shfl_xor(a0, o, 64); }
  if (lane < 50) sample[base + lane] = gv / sg;
  double dga0 = digamma_d((double)a0);
  double gl = 0.0, tm = 0.0;
  if (lane < 50){
    double ad = (double)av;
    gl = lgamma(ad);
    tm = (ad - 1.0) * (digamma_d(ad) - dga0);
  }
  for (int o = 32; o > 0; o >>= 1){ gl += __shfl_xor(gl, o, 64); tm += __shfl_xor(tm, o, 64); }
  if (lane == 0)
    kld[row] = (float)(lgamma((double)a0) - gl - lgamma(50.0) + tm);
}

// ---- K6 round 14: fused z + partials, latency-tuned.
// 32-row blocks (grid 64x196 = 12544, ~49/CU), 2 passes/wave, f32 lane-local
// partials + f32 butterflies (half the shuffle ops, fewer VGPRs), and bows
// prefetched BEFORE the k-loop so the HBM latency hides under 200 FMAs.

// K6a fused: z + partials -> partF[row][196][3] (f32)
__global__ __launch_bounds__(256) void k6a_f(const float* __restrict__ sample,
                                             const float* __restrict__ Wd,
                                             const float* __restrict__ bd,
                                             const float* __restrict__ bows,
                                             float* __restrict__ zout,
                                             float* __restrict__ partF){
  __shared__ float s_lds[32*52];
  int rowb = blockIdx.x * 32;
  int colb = blockIdx.y * 256;
  int tid = threadIdx.x;
  for (int idx = tid; idx < 32*52; idx += 256){
    int r = idx / 52, k = idx - 52*r;
    s_lds[idx] = (k < 50) ? sample[(size_t)(rowb + r)*50 + k] : 0.0f;
  }
  __syncthreads();
  int lane = tid & 63, w = tid >> 6;
  int col = colb + 4*lane;
  bool act = col < 50000;
  float4 bd4 = {0.0f, 0.0f, 0.0f, 0.0f};
  if (act) bd4 = *(const float4*)(bd + col);
  for (int p = 0; p < 2; ++p){
    int r0 = w*8 + p*4;
    const float* sb = s_lds + r0*52;
    float4 acc[4] = {};
    float4 bw[4];
    if (act){
      // prefetch bows rows for this pass — retire under the k-loop below
      #pragma unroll
      for (int r = 0; r < 4; ++r)
        bw[r] = *(const float4*)(bows + (size_t)(rowb + r0 + r)*50000 + col);
      #pragma unroll
      for (int q = 0; q < 12; ++q){
        #pragma unroll
        for (int kk = 0; kk < 4; ++kk){
          int k = q*4 + kk;
          float4 wd4 = *(const float4*)(Wd + (size_t)k*50000 + col);
          #pragma unroll
          for (int r = 0; r < 4; ++r){
            float sv = sb[r*52 + k];
            acc[r].x = fmaf(sv, wd4.x, acc[r].x);
            acc[r].y = fmaf(sv, wd4.y, acc[r].y);
            acc[r].z = fmaf(sv, wd4.z, acc[r].z);
            acc[r].w = fmaf(sv, wd4.w, acc[r].w);
          }
        }
      }
      #pragma unroll
      for (int kk = 0; kk < 2; ++kk){
        int k = 48 + kk;
        float4 wd4 = *(const float4*)(Wd + (size_t)k*50000 + col);
        #pragma unroll
        for (int r = 0; r < 4; ++r){
          float sv = sb[r*52 + k];
          acc[r].x = fmaf(sv, wd4.x, acc[r].x);
          acc[r].y = fmaf(sv, wd4.y, acc[r].y);
          acc[r].z = fmaf(sv, wd4.z, acc[r].z);
          acc[r].w = fmaf(sv, wd4.w, acc[r].w);
        }
      }
    }
    #pragma unroll
    for (int r = 0; r < 4; ++r){
      float se = 0.0f, s1 = 0.0f, sbw = 0.0f;
      if (act){
        float zx = bd4.x + acc[r].x;
        float zy = bd4.y + acc[r].y;
        float zz = bd4.z + acc[r].z;
        float zw = bd4.w + acc[r].w;
        float4 z4; z4.x = zx; z4.y = zy; z4.z = zz; z4.w = zw;
        *(float4*)(zout + (size_t)(rowb + r0 + r)*50000 + col) = z4;
        se  = (expf(zx) + expf(zy)) + (expf(zz) + expf(zw));
        s1  = ((zx*bw[r].x + zy*bw[r].y) + (zz*bw[r].z + zw*bw[r].w));
        sbw = ((bw[r].x + bw[r].y) + (bw[r].z + bw[r].w));
      }
      for (int o = 32; o > 0; o >>= 1){
        se  += __shfl_xor(se,  o, 64);
        s1  += __shfl_xor(s1,  o, 64);
        sbw += __shfl_xor(sbw, o, 64);
      }
      if (lane == 0){
        size_t off = ((size_t)(rowb + r0 + r)*196 + blockIdx.y)*3;
        partF[off] = se; partF[off+1] = s1; partF[off+2] = sbw;
      }
    }
  }
}

// K6m (f32 partials): reduce -> lse, rec (f64 accumulation)
__global__ void k6m_f(const float* __restrict__ partF, float* __restrict__ lse,
                      float* __restrict__ rec){
  int row = blockIdx.x*256 + threadIdx.x;      // 2048
  double se = 0, s1 = 0, sb = 0;
  const float* p = partF + (size_t)row*588;    // 196*3
  for (int q = 0; q < 196; ++q){ se += (double)p[3*q]; s1 += (double)p[3*q+1]; sb += (double)p[3*q+2]; }
  double l = log(se);
  lse[row] = (float)l;
  rec[row] = (float)(l*sb - s1);
}

// K6z: in-place logits = z - lse[row]; grid (49, 2048), 1 float4/thread
__global__ void k6z(float* __restrict__ logits, const float* __restrict__ lse){
  int row = blockIdx.y;
  int col4 = blockIdx.x*256 + threadIdx.x;     // 12500 float4 per row
  if (col4 < 12500){
    float lf = lse[row];
    float4* p = (float4*)(logits + (size_t)row*50000) + col4;
    float4 z = *p;
    z.x -= lf; z.y -= lf; z.z -= lf; z.w -= lf;
    *p = z;
  }
}

// ---- Fallback path (ws too small): exact R5 split kernels, f64 partials
// in the logits-region scratch (k6b recomputes z and overwrites).
__global__ __launch_bounds__(256) void k6a_sep(const float* __restrict__ sample,
                                               const float* __restrict__ Wd,
                                               const float* __restrict__ bd,
                                               const float* __restrict__ bows,
                                               double* __restrict__ part){
  __shared__ float s_lds[64*52];
  int rowb = blockIdx.x * 64;
  int colb = blockIdx.y * 256;
  int tid = threadIdx.x;
  for (int idx = tid; idx < 64*52; idx += 256){
    int r = idx / 52, k = idx - 52*r;
    s_lds[idx] = (k < 50) ? sample[(size_t)(rowb + r)*50 + k] : 0.0f;
  }
  __syncthreads();
  int lane = tid & 63, w = tid >> 6;
  int col = colb + 4*lane;
  bool act = col < 50000;
  float4 bd4 = {0.0f, 0.0f, 0.0f, 0.0f};
  if (act) bd4 = *(const float4*)(bd + col);
  for (int p = 0; p < 4; ++p){
    int r0 = w*16 + p*4;
    float4 acc[4] = {};
    const float* sb = s_lds + r0*52;
    if (act){
      #pragma unroll
      for (int q = 0; q < 12; ++q){
        #pragma unroll
        for (int kk = 0; kk < 4; ++kk){
          int k = q*4 + kk;
          float4 wd4 = *(const float4*)(Wd + (size_t)k*50000 + col);
          #pragma unroll
          for (int r = 0; r < 4; ++r){
            float sv = sb[r*52 + k];
            acc[r].x = fmaf(sv, wd4.x, acc[r].x);
            acc[r].y = fmaf(sv, wd4.y, acc[r].y);
            acc[r].z = fmaf(sv, wd4.z, acc[r].z);
            acc[r].w = fmaf(sv, wd4.w, acc[r].w);
          }
        }
      }
      #pragma unroll
      for (int kk = 0; kk < 2; ++kk){
        int k = 48 + kk;
        float4 wd4 = *(const float4*)(Wd + (size_t)k*50000 + col);
        #pragma unroll
        for (int r = 0; r < 4; ++r){
          float sv = sb[r*52 + k];
          acc[r].x = fmaf(sv, wd4.x, acc[r].x);
          acc[r].y = fmaf(sv, wd4.y, acc[r].y);
          acc[r].z = fmaf(sv, wd4.z, acc[r].z);
          acc[r].w = fmaf(sv, wd4.w, acc[r].w);
        }
      }
    }
    #pragma unroll
    for (int r = 0; r < 4; ++r){
      double se = 0.0, s1 = 0.0, sbw = 0.0;
      if (act){
        float4 bw = *(const float4*)(bows + (size_t)(rowb + r0 + r)*50000 + col);
        float zx = bd4.x + acc[r].x;
        float zy = bd4.y + acc[r].y;
        float zz = bd4.z + acc[r].z;
        float zw = bd4.w + acc[r].w;
        se  = ((double)expf(zx) + (double)expf(zy)) + ((double)expf(zz) + (double)expf(zw));
        s1  = (((double)zx*bw.x + (double)zy*bw.y) + ((double)zz*bw.z + (double)zw*bw.w));
        sbw = (((double)bw.x + (double)bw.y) + ((double)bw.z + (double)bw.w));
      }
      for (int o = 32; o > 0; o >>= 1){
        se  += __shfl_xor(se,  o, 64);
        s1  += __shfl_xor(s1,  o, 64);
        sbw += __shfl_xor(sbw, o, 64);
      }
      if (lane == 0){
        size_t off = ((size_t)(rowb + r0 + r)*196 + blockIdx.y)*3;
        part[off] = se; part[off+1] = s1; part[off+2] = sbw;
      }
    }
  }
}

__global__ void k6m_d(const double* __restrict__ part, float* __restrict__ lse,
                      float* __restrict__ rec){
  int row = blockIdx.x*256 + threadIdx.x;      // 2048
  double se = 0, s1 = 0, sb = 0;
  const double* p = part + (size_t)row*588;    // 196*3
  for (int q = 0; q < 196; ++q){ se += p[3*q]; s1 += p[3*q+1]; sb += p[3*q+2]; }
  double l = log(se);
  lse[row] = (float)l;
  rec[row] = (float)(l*sb - s1);
}

__global__ __launch_bounds__(256) void k6b_sep(const float* __restrict__ sample,
                                               const float* __restrict__ Wd,
                                               const float* __restrict__ bd,
                                               const float* __restrict__ lse,
                                               float* __restrict__ logits){
  __shared__ float s_lds[64*52];
  int rowb = blockIdx.x * 64;
  int colb = blockIdx.y * 256;
  int tid = threadIdx.x;
  for (int idx = tid; idx < 64*52; idx += 256){
    int r = idx / 52, k = idx - 52*r;
    s_lds[idx] = (k < 50) ? sample[(size_t)(rowb + r)*50 + k] : 0.0f;
  }
  __syncthreads();
  int lane = tid & 63, w = tid >> 6;
  int col = colb + 4*lane;
  bool act = col < 50000;
  float4 bd4 = {0.0f, 0.0f, 0.0f, 0.0f};
  if (act) bd4 = *(const float4*)(bd + col);
  for (int p = 0; p < 4; ++p){
    int r0 = w*16 + p*4;
    float4 acc[4] = {};
    const float* sb = s_lds + r0*52;
    if (act){
      #pragma unroll
      for (int q = 0; q < 12; ++q){
        #pragma unroll
        for (int kk = 0; kk < 4; ++kk){
          int k = q*4 + kk;
          float4 wd4 = *(const float4*)(Wd + (size_t)k*50000 + col);
          #pragma unroll
          for (int r = 0; r < 4; ++r){
            float sv = sb[r*52 + k];
            acc[r].x = fmaf(sv, wd4.x, acc[r].x);
            acc[r].y = fmaf(sv, wd4.y, acc[r].y);
            acc[r].z = fmaf(sv, wd4.z, acc[r].z);
            acc[r].w = fmaf(sv, wd4.w, acc[r].w);
          }
        }
      }
      #pragma unroll
      for (int kk = 0; kk < 2; ++kk){
        int k = 48 + kk;
        float4 wd4 = *(const float4*)(Wd + (size_t)k*50000 + col);
        #pragma unroll
        for (int r = 0; r < 4; ++r){
          float sv = sb[r*52 + k];
          acc[r].x = fmaf(sv, wd4.x, acc[r].x);
          acc[r].y = fmaf(sv, wd4.y, acc[r].y);
          acc[r].z = fmaf(sv, wd4.z, acc[r].z);
          acc[r].w = fmaf(sv, wd4.w, acc[r].w);
        }
      }
      #pragma unroll
      for (int r = 0; r < 4; ++r){
        float lf = lse[rowb + r0 + r];
        float4 z;
        z.x = (bd4.x + acc[r].x) - lf;
        z.y = (bd4.y + acc[r].y) - lf;
        z.z = (bd4.z + acc[r].z) - lf;
        z.w = (bd4.w + acc[r].w) - lf;
        *(float4*)(logits + (size_t)(rowb + r0 + r)*50000 + col) = z;
      }
    }
  }
}

// ============================ launcher ============================
extern "C" void kernel_launch(void* const* d_in, const int* in_sizes, int n_in,
                              void* d_out, int out_size, void* d_ws, size_t ws_size,
                              hipStream_t stream){
  (void)in_sizes; (void)n_in; (void)out_size;
  const float* bows = (const float*)d_in[0];
  const float* W1   = (const float*)d_in[1];
  const float* b1   = (const float*)d_in[2];
  const float* W2   = (const float*)d_in[3];
  const float* b2   = (const float*)d_in[4];
  const float* Wt   = (const float*)d_in[5];
  const float* bt   = (const float*)d_in[6];
  const float* bng  = (const float*)d_in[7];
  const float* bnb  = (const float*)d_in[8];
  const float* Wd   = (const float*)d_in[9];
  const float* bd   = (const float*)d_in[10];

  float* out    = (float*)d_out;
  float* sample = out;                                     // [2048*50]
  float* logits = out + 102400;                            // [2048*50000]
  float* kld    = out + 102400 + (size_t)2048*50000;       // [2048]
  float* rec    = kld + 2048;                              // [2048]

  // Scratch in the logits region — dead before k6 writes z/logits there.
  float*  pre_part = logits;                               // [125][2048][100]
  float*  h1    = pre_part + (size_t)125*2048*100;         // 204800
  float*  h2    = h1 + 204800;
  float*  tbuf  = h2 + 204800;                             // 102400
  float*  abuf  = tbuf + 102400;
  float*  gbuf  = abuf + 102400;
  float*  musig = gbuf + 102400;                           // 128

  k1_gemm<<<dim3(32, 125), 256, 0, stream>>>(bows, W1, pre_part);
  k2a<<<800, 256, 0, stream>>>(pre_part, b1, h1);
  k2b<<<800, 256, 0, stream>>>(h1, W2, b2, h2);
  k2c<<<400, 256, 0, stream>>>(h2, Wt, bt, tbuf);
  k3_bn<<<50, 256, 0, stream>>>(tbuf, musig);
  k4_gamma<<<400, 256, 0, stream>>>(tbuf, musig, bng, bnb, abuf, gbuf);
  k5_row<<<512, 256, 0, stream>>>(gbuf, abuf, sample, kld);

  const size_t needF = (size_t)2048*196*3*sizeof(float) + 2048*sizeof(float);
  if (ws_size >= needF){
    // Fused path: z once (written into logits), f32 partials in d_ws.
    float* partF = (float*)d_ws;                 // [2048][196][3] f32
    float* lsew  = partF + (size_t)2048*196*3;   // 2048 f32
    k6a_f<<<dim3(64, 196), 256, 0, stream>>>(sample, Wd, bd, bows, logits, partF);
    k6m_f<<<8, 256, 0, stream>>>(partF, lsew, rec);
    k6z<<<dim3(49, 2048), 256, 0, stream>>>(logits, lsew);
  } else {
    // Fallback: proven R5 split path; f64 partials in logits-region scratch.
    double* partD = (double*)(musig + 128);      // [2048][196][3] f64
    float*  lsew  = (float*)d_ws;                // 2048 f32
    k6a_sep<<<dim3(32, 196), 256, 0, stream>>>(sample, Wd, bd, bows, partD);
    k6m_d<<<8, 256, 0, stream>>>(partD, lsew, rec);
    k6b_sep<<<dim3(32, 196), 256, 0, stream>>>(sample, Wd, bd, lsew, logits);
  }
}